// Round 1
// baseline (2285.025 us; speedup 1.0000x reference)
//
#include <hip/hip_runtime.h>
#include <cstdint>
#include <cstddef>

#define N_TOK 4096
#define DIM   1024
#define NEXP  8
#define HID   4096
#define TWO_H 8192
#define CAP   1280

typedef __bf16 bf16x8 __attribute__((ext_vector_type(8)));
typedef float  f32x4  __attribute__((ext_vector_type(4)));

__device__ __forceinline__ unsigned short f2bf(float f) {
  union { float f; unsigned u; } v; v.f = f;
  unsigned r = v.u + 0x7FFF + ((v.u >> 16) & 1);   // RNE
  return (unsigned short)(r >> 16);
}
__device__ __forceinline__ float bf2f(unsigned short b) {
  union { unsigned u; float f; } v; v.u = ((unsigned)b) << 16;
  return v.f;
}

// ---------------- zero accumulators ----------------
__global__ void k_zero(float* imp, float* zsum) {
  if (threadIdx.x < NEXP) imp[threadIdx.x] = 0.f;
  if (threadIdx.x == 0) zsum[0] = 0.f;
}

// ---------------- W1 [E][D][2H] fp32 -> packed W1t [E][2H][D] bf16 ----------------
// packed row 2h+0 = W1[:, h] (a-column), row 2h+1 = W1[:, H+h] (g-column)
__global__ void k_conv_w1(const float* __restrict__ W1, unsigned short* __restrict__ W1t) {
  __shared__ float tA[32][33];
  __shared__ float tG[32][33];
  int h0 = blockIdx.x * 32, d0 = blockIdx.y * 32, e = blockIdx.z;
  int tx = threadIdx.x & 31, ty = threadIdx.x >> 5;  // ty 0..7
  const float* src = W1 + (size_t)e * DIM * TWO_H;
  for (int i = 0; i < 32; i += 8) {
    int d = d0 + ty + i;
    tA[ty + i][tx] = src[(size_t)d * TWO_H + h0 + tx];
    tG[ty + i][tx] = src[(size_t)d * TWO_H + HID + h0 + tx];
  }
  __syncthreads();
  unsigned short* dst = W1t + (size_t)e * TWO_H * DIM;
  for (int i = 0; i < 64; i += 8) {
    int r = ty + i;                  // 0..63 local packed row
    int hh = r >> 1, p = r & 1;
    float v = p ? tG[tx][hh] : tA[tx][hh];
    dst[(size_t)(2 * h0 + r) * DIM + d0 + tx] = f2bf(v);
  }
}

// ---------------- W2 [E][H][D] fp32 -> W2t [E][D][H] bf16 ----------------
__global__ void k_conv_w2(const float* __restrict__ W2, unsigned short* __restrict__ W2t) {
  __shared__ float t[32][33];
  int d0 = blockIdx.x * 32, h0 = blockIdx.y * 32, e = blockIdx.z;
  int tx = threadIdx.x & 31, ty = threadIdx.x >> 5;
  const float* src = W2 + (size_t)e * HID * DIM;
  for (int i = 0; i < 32; i += 8)
    t[ty + i][tx] = src[(size_t)(h0 + ty + i) * DIM + d0 + tx];
  __syncthreads();
  unsigned short* dst = W2t + (size_t)e * DIM * HID;
  for (int i = 0; i < 32; i += 8)
    dst[(size_t)(d0 + ty + i) * HID + h0 + tx] = f2bf(t[tx][ty + i]);
}

// ---------------- b1 [E][2H] -> packed b1p [E][2H] (pairs a,g) ----------------
__global__ void k_pack_b1(const float* __restrict__ b1, float* __restrict__ b1p) {
  int g = blockIdx.x * blockDim.x + threadIdx.x;
  int e = g >> 13, r = g & (TWO_H - 1);
  int h = r >> 1, p = r & 1;
  b1p[g] = b1[e * TWO_H + p * HID + h];
}

// ---------------- router: logits, softmax stats, top-2, gates ----------------
__global__ void __launch_bounds__(256) k_router(
    const float* __restrict__ x, const float* __restrict__ Wr, const float* __restrict__ br,
    int* __restrict__ idx, float* __restrict__ gate,
    float* __restrict__ imp, float* __restrict__ zsum) {
  int n = blockIdx.x, tid = threadIdx.x;
  int e = tid & 7, part = tid >> 3;                 // 32 partials per expert
  const float* xr = x + (size_t)n * DIM;
  float s = 0.f;
  for (int j = 0; j < DIM / 32; ++j) {
    int k = part + j * 32;
    s += xr[k] * Wr[k * NEXP + e];
  }
  __shared__ float red[256];
  __shared__ float lg[NEXP];
  red[tid] = s;
  __syncthreads();
  if (tid < NEXP) {
    float t = br[tid];
    for (int j = 0; j < 32; ++j) t += red[tid + j * 8];
    lg[tid] = t;
  }
  __syncthreads();
  if (tid == 0) {
    float mx = lg[0];
    for (int i = 1; i < 8; ++i) mx = fmaxf(mx, lg[i]);
    float ex[8], den = 0.f, zs = 0.f;
    for (int i = 0; i < 8; ++i) { ex[i] = expf(lg[i] - mx); den += ex[i]; zs += lg[i] * lg[i]; }
    atomicAdd(zsum, zs);
    for (int i = 0; i < 8; ++i) atomicAdd(&imp[i], ex[i] / den);
    int i1 = 0;
    for (int i = 1; i < 8; ++i) if (lg[i] > lg[i1]) i1 = i;     // ties -> lowest idx, like top_k
    int i2 = -1;
    for (int i = 0; i < 8; ++i) { if (i == i1) continue; if (i2 < 0 || lg[i] > lg[i2]) i2 = i; }
    float e2 = expf(lg[i2] - lg[i1]);
    float g1 = 1.f / (1.f + e2);
    idx[n * 2] = i1; idx[n * 2 + 1] = i2;
    gate[n * 2] = g1; gate[n * 2 + 1] = 1.f - g1;
  }
}

// ---------------- per-expert sequential position scan (flat order s = k*N + n) -----
__global__ void k_scan(const int* __restrict__ idx, int* __restrict__ pos, int* __restrict__ cnt) {
  int wave = threadIdx.x >> 6, lane = threadIdx.x & 63;  // wave == expert id
  int base = 0;
  for (int c = 0; c < (2 * N_TOK) / 64; ++c) {
    int s = c * 64 + lane;
    int n = s & (N_TOK - 1), k = s >> 12;
    int e = idx[n * 2 + k];
    unsigned long long m = __ballot(e == wave);
    if (e == wave) pos[s] = base + __popcll(m & ((1ull << lane) - 1ull));
    base += __popcll(m);
  }
  if (lane == 0) cnt[wave] = base;
}

// ---------------- renormalized kept gates ----------------
__global__ void k_weights(const float* __restrict__ gate, const int* __restrict__ pos,
                          float* __restrict__ wn) {
  int n = blockIdx.x * blockDim.x + threadIdx.x;
  if (n >= N_TOK) return;
  float g0 = gate[n * 2], g1 = gate[n * 2 + 1];
  float k0 = (pos[n] < CAP) ? g0 : 0.f;
  float k1 = (pos[N_TOK + n] < CAP) ? g1 : 0.f;
  float den = fmaxf(k0 + k1, 1e-8f);
  wn[n * 2] = k0 / den; wn[n * 2 + 1] = k1 / den;
}

// ---------------- gather + per-expert LayerNorm -> Xn bf16 [E][CAP][D] ----------------
__global__ void __launch_bounds__(256) k_gather_ln(
    const float* __restrict__ x, const float* __restrict__ lns, const float* __restrict__ lnb,
    const int* __restrict__ idx, const int* __restrict__ pos, unsigned short* __restrict__ Xn) {
  int s = blockIdx.x;
  int p = pos[s];
  if (p >= CAP) return;                       // dropped slot; Xn row stays poison (tiny bf16, *0 later)
  int n = s & (N_TOK - 1), k = s >> 12;
  int e = idx[n * 2 + k];
  const float* xr = x + (size_t)n * DIM;
  int tid = threadIdx.x;
  float v[4], sum = 0.f, sq = 0.f;
  for (int i = 0; i < 4; ++i) { v[i] = xr[tid + i * 256]; sum += v[i]; sq += v[i] * v[i]; }
  for (int o = 32; o > 0; o >>= 1) { sum += __shfl_down(sum, o); sq += __shfl_down(sq, o); }
  __shared__ float ws[8];
  int wv = tid >> 6, ln = tid & 63;
  if (ln == 0) { ws[wv] = sum; ws[4 + wv] = sq; }
  __syncthreads();
  sum = ws[0] + ws[1] + ws[2] + ws[3];
  sq  = ws[4] + ws[5] + ws[6] + ws[7];
  float mu = sum * (1.f / DIM);
  float var = sq * (1.f / DIM) - mu * mu;
  float rs = rsqrtf(var + 1e-5f);
  unsigned short* orow = Xn + ((size_t)e * CAP + p) * DIM;
  const float* sc = lns + (size_t)e * DIM;
  const float* bi = lnb + (size_t)e * DIM;
  for (int i = 0; i < 4; ++i) {
    int d = tid + i * 256;
    orow[d] = f2bf((v[i] - mu) * rs * sc[d] + bi[d]);
  }
}

// ---------------- bf16 MFMA GEMM: C[m][n] = sum_k A[m][k] * B[n][k]  (B is N-major, B^T) ----
// 128x128 tile, BK=64, 4 waves (2x2 of 64x64), 16x16x32 MFMA.
// GLU=true: B rows are packed (a,g) pairs; epilogue writes V[m][n/2] = (a+b1a)*sigmoid(g+b1g) bf16
template<bool GLU>
__global__ void __launch_bounds__(256) k_gemm(
    const unsigned short* __restrict__ A,   // [E][M][K]
    const unsigned short* __restrict__ B,   // [E][Nn][K]
    const float* __restrict__ bias,         // b1p [E][2H] (only used if GLU)
    unsigned short* __restrict__ Cout,      // GLU: [E][M][Nn/2] else [E][M][Nn]
    int M, int Nn, int K) {
  __shared__ __align__(16) unsigned short sA[128][72];
  __shared__ __align__(16) unsigned short sB[128][72];
  int e  = blockIdx.z;
  int m0 = blockIdx.y * 128;
  int n0 = blockIdx.x * 128;
  const unsigned short* Ae = A + (size_t)e * M * K;
  const unsigned short* Be = B + (size_t)e * Nn * K;
  int tid = threadIdx.x;
  int lane = tid & 63, wave = tid >> 6;
  int wm = (wave >> 1) * 64, wn = (wave & 1) * 64;
  int quad = lane >> 4, l16 = lane & 15;
  f32x4 acc[4][4];
  for (int i = 0; i < 4; ++i)
    for (int j = 0; j < 4; ++j) acc[i][j] = f32x4{0.f, 0.f, 0.f, 0.f};

  int srow = tid >> 3;              // 0..31
  int schunk = (tid & 7) * 8;       // element offset within 64-wide K slab
  for (int k0 = 0; k0 < K; k0 += 64) {
    __syncthreads();
    for (int i = 0; i < 4; ++i) {
      int r = srow + i * 32;
      *(int4*)&sA[r][schunk] = *(const int4*)&Ae[(size_t)(m0 + r) * K + k0 + schunk];
      *(int4*)&sB[r][schunk] = *(const int4*)&Be[(size_t)(n0 + r) * K + k0 + schunk];
    }
    __syncthreads();
    for (int kk = 0; kk < 64; kk += 32) {
      bf16x8 aF[4], bF[4];
      for (int i = 0; i < 4; ++i) {
        aF[i] = *(const bf16x8*)&sA[wm + i * 16 + l16][kk + quad * 8];
        bF[i] = *(const bf16x8*)&sB[wn + i * 16 + l16][kk + quad * 8];
      }
      for (int i = 0; i < 4; ++i)
        for (int j = 0; j < 4; ++j)
          acc[i][j] = __builtin_amdgcn_mfma_f32_16x16x32_bf16(aF[i], bF[j], acc[i][j], 0, 0, 0);
    }
  }
  if (GLU) {
    const float* bp = bias + (size_t)e * TWO_H;
    unsigned short* Ce = Cout + (size_t)e * M * (Nn >> 1);
    for (int i = 0; i < 4; ++i)
      for (int j = 0; j < 4; ++j) {
        int pn = n0 + wn + j * 16 + l16;
        float b = bp[pn];
        for (int r = 0; r < 4; ++r) {
          int m = m0 + wm + i * 16 + quad * 4 + r;
          float u = acc[i][j][r] + b;          // includes bias for both a and g lanes
          float g = __shfl_xor(u, 1);          // partner column (pn^1)
          if ((l16 & 1) == 0) {                // even col = a, partner = g
            float vv = u / (1.f + __expf(-g));
            Ce[(size_t)m * (Nn >> 1) + (pn >> 1)] = f2bf(vv);
          }
        }
      }
  } else {
    unsigned short* Ce = Cout + (size_t)e * M * Nn;
    for (int i = 0; i < 4; ++i)
      for (int j = 0; j < 4; ++j) {
        int nn = n0 + wn + j * 16 + l16;
        for (int r = 0; r < 4; ++r) {
          int m = m0 + wm + i * 16 + quad * 4 + r;
          Ce[(size_t)m * Nn + nn] = f2bf(acc[i][j][r]);
        }
      }
  }
}

// ---------------- combine: y[n] = sum_k w_k * (Yexp[e_k][p_k] + b2[e_k]) ----------------
__global__ void __launch_bounds__(256) k_gather_out(
    const unsigned short* __restrict__ Yexp, const float* __restrict__ b2,
    const int* __restrict__ idx, const int* __restrict__ pos,
    const float* __restrict__ wn, float* __restrict__ y) {
  int n = blockIdx.x, tid = threadIdx.x;
  int e0 = idx[n * 2], e1 = idx[n * 2 + 1];
  int p0 = min(pos[n], CAP - 1), p1 = min(pos[N_TOK + n], CAP - 1);
  float w0 = wn[n * 2], w1 = wn[n * 2 + 1];
  const unsigned short* r0 = Yexp + ((size_t)e0 * CAP + p0) * DIM;
  const unsigned short* r1 = Yexp + ((size_t)e1 * CAP + p1) * DIM;
  const float* bb0 = b2 + (size_t)e0 * DIM;
  const float* bb1 = b2 + (size_t)e1 * DIM;
  float* yr = y + (size_t)n * DIM;
  for (int i = 0; i < 4; ++i) {
    int d = tid + i * 256;
    yr[d] = w0 * (bf2f(r0[d]) + bb0[d]) + w1 * (bf2f(r1[d]) + bb1[d]);
  }
}

// ---------------- scalar losses ----------------
__global__ void k_losses(const float* __restrict__ imp, const int* __restrict__ cnt,
                         const float* __restrict__ zsum, float* __restrict__ out) {
  if (threadIdx.x != 0 || blockIdx.x != 0) return;
  double li[8], ll[8], mi = 0.0, ml = 0.0;
  for (int i = 0; i < 8; ++i) {
    li[i] = imp[i];
    ll[i] = (double)min(cnt[i], CAP);
    mi += li[i]; ml += ll[i];
  }
  mi /= 8.0; ml /= 8.0;
  double vi = 0.0, vl = 0.0;
  for (int i = 0; i < 8; ++i) { vi += (li[i] - mi) * (li[i] - mi); vl += (ll[i] - ml) * (ll[i] - ml); }
  vi /= 8.0; vl /= 8.0;
  const double eps = 1e-9;
  double cvi = vi / (fmax(mi, eps) * fmax(mi, eps) + eps);
  double cvl = vl / (fmax(ml, eps) * fmax(ml, eps) + eps);
  out[0] = (float)(0.5 * (cvi + cvl));
  out[1] = (float)((double)zsum[0] / (double)(N_TOK * NEXP) * 1e-4);
}

extern "C" void kernel_launch(void* const* d_in, const int* in_sizes, int n_in,
                              void* d_out, int out_size, void* d_ws, size_t ws_size,
                              hipStream_t stream) {
  const float* h   = (const float*)d_in[0];
  const float* Wr  = (const float*)d_in[1];
  const float* br  = (const float*)d_in[2];
  const float* lns = (const float*)d_in[3];
  const float* lnb = (const float*)d_in[4];
  const float* W1  = (const float*)d_in[5];
  const float* b1  = (const float*)d_in[6];
  const float* W2  = (const float*)d_in[7];
  const float* b2  = (const float*)d_in[8];
  float* out = (float*)d_out;

  char* ws = (char*)d_ws;
  size_t off = 0;
  auto alloc = [&](size_t bytes) { char* p = ws + off; off += (bytes + 255) & ~(size_t)255; return p; };
  unsigned short* W1t = (unsigned short*)alloc((size_t)NEXP * TWO_H * DIM * 2);  // 134 MB
  unsigned short* W2t = (unsigned short*)alloc((size_t)NEXP * DIM * HID * 2);    // 67 MB
  unsigned short* Xn  = (unsigned short*)alloc((size_t)NEXP * CAP * DIM * 2);    // 21 MB
  unsigned short* V   = (unsigned short*)alloc((size_t)NEXP * CAP * HID * 2);    // 84 MB
  unsigned short* Yx  = (unsigned short*)alloc((size_t)NEXP * CAP * DIM * 2);    // 21 MB
  float* b1p  = (float*)alloc((size_t)NEXP * TWO_H * 4);
  int*   idx  = (int*)alloc((size_t)N_TOK * 2 * 4);
  float* gate = (float*)alloc((size_t)N_TOK * 2 * 4);
  float* wn   = (float*)alloc((size_t)N_TOK * 2 * 4);
  int*   pos  = (int*)alloc((size_t)2 * N_TOK * 4);
  int*   cnt  = (int*)alloc(64);
  float* imp  = (float*)alloc(64);
  float* zsum = (float*)alloc(64);
  (void)ws_size; (void)in_sizes; (void)n_in; (void)out_size;

  k_zero<<<dim3(1), dim3(64), 0, stream>>>(imp, zsum);
  k_conv_w1<<<dim3(HID / 32, DIM / 32, NEXP), dim3(256), 0, stream>>>(W1, W1t);
  k_conv_w2<<<dim3(DIM / 32, HID / 32, NEXP), dim3(256), 0, stream>>>(W2, W2t);
  k_pack_b1<<<dim3(NEXP * TWO_H / 256), dim3(256), 0, stream>>>(b1, b1p);
  k_router<<<dim3(N_TOK), dim3(256), 0, stream>>>(h, Wr, br, idx, gate, imp, zsum);
  k_scan<<<dim3(1), dim3(512), 0, stream>>>(idx, pos, cnt);
  k_weights<<<dim3(16), dim3(256), 0, stream>>>(gate, pos, wn);
  k_gather_ln<<<dim3(2 * N_TOK), dim3(256), 0, stream>>>(h, lns, lnb, idx, pos, Xn);
  k_gemm<true><<<dim3(TWO_H / 128, CAP / 128, NEXP), dim3(256), 0, stream>>>(
      Xn, W1t, b1p, V, CAP, TWO_H, DIM);
  k_gemm<false><<<dim3(DIM / 128, CAP / 128, NEXP), dim3(256), 0, stream>>>(
      V, W2t, b1p, Yx, CAP, DIM, HID);
  k_gather_out<<<dim3(N_TOK), dim3(256), 0, stream>>>(Yx, b2, idx, pos, wn, out);
  k_losses<<<dim3(1), dim3(64), 0, stream>>>(imp, cnt, zsum, out + (size_t)N_TOK * DIM);
}

// Round 2
// 1453.878 us; speedup vs baseline: 1.5717x; 1.5717x over previous
//
#include <hip/hip_runtime.h>
#include <cstdint>
#include <cstddef>

#define N_TOK 4096
#define DIM   1024
#define NEXP  8
#define HID   4096
#define TWO_H 8192
#define CAP   1280

typedef __bf16 bf16x8 __attribute__((ext_vector_type(8)));
typedef float  f32x4  __attribute__((ext_vector_type(4)));

__device__ __forceinline__ unsigned short f2bf(float f) {
  union { float f; unsigned u; } v; v.f = f;
  unsigned r = v.u + 0x7FFF + ((v.u >> 16) & 1);   // RNE
  return (unsigned short)(r >> 16);
}
__device__ __forceinline__ float bf2f(unsigned short b) {
  union { unsigned u; float f; } v; v.u = ((unsigned)b) << 16;
  return v.f;
}

// ---------------- zero accumulators ----------------
__global__ void k_zero(float* imp, float* zsum) {
  if (threadIdx.x < NEXP) imp[threadIdx.x] = 0.f;
  if (threadIdx.x == 0) zsum[0] = 0.f;
}

// ---------------- W1 [E][D][2H] fp32 -> packed W1t [E][2H][D] bf16 ----------------
// packed row 2h+0 = W1[:, h] (a-column), row 2h+1 = W1[:, H+h] (g-column)
__global__ void k_conv_w1(const float* __restrict__ W1, unsigned short* __restrict__ W1t) {
  __shared__ float tA[32][33];
  __shared__ float tG[32][33];
  int h0 = blockIdx.x * 32, d0 = blockIdx.y * 32, e = blockIdx.z;
  int tx = threadIdx.x & 31, ty = threadIdx.x >> 5;  // ty 0..7
  const float* src = W1 + (size_t)e * DIM * TWO_H;
  for (int i = 0; i < 32; i += 8) {
    int d = d0 + ty + i;
    tA[ty + i][tx] = src[(size_t)d * TWO_H + h0 + tx];
    tG[ty + i][tx] = src[(size_t)d * TWO_H + HID + h0 + tx];
  }
  __syncthreads();
  unsigned short* dst = W1t + (size_t)e * TWO_H * DIM;
  for (int i = 0; i < 64; i += 8) {
    int r = ty + i;                  // 0..63 local packed row
    int hh = r >> 1, p = r & 1;
    float v = p ? tG[tx][hh] : tA[tx][hh];
    dst[(size_t)(2 * h0 + r) * DIM + d0 + tx] = f2bf(v);
  }
}

// ---------------- W2 [E][H][D] fp32 -> W2t [E][D][H] bf16 ----------------
__global__ void k_conv_w2(const float* __restrict__ W2, unsigned short* __restrict__ W2t) {
  __shared__ float t[32][33];
  int d0 = blockIdx.x * 32, h0 = blockIdx.y * 32, e = blockIdx.z;
  int tx = threadIdx.x & 31, ty = threadIdx.x >> 5;
  const float* src = W2 + (size_t)e * HID * DIM;
  for (int i = 0; i < 32; i += 8)
    t[ty + i][tx] = src[(size_t)(h0 + ty + i) * DIM + d0 + tx];
  __syncthreads();
  unsigned short* dst = W2t + (size_t)e * DIM * HID;
  for (int i = 0; i < 32; i += 8)
    dst[(size_t)(d0 + ty + i) * HID + h0 + tx] = f2bf(t[tx][ty + i]);
}

// ---------------- b1 [E][2H] -> packed b1p [E][2H] (pairs a,g) ----------------
__global__ void k_pack_b1(const float* __restrict__ b1, float* __restrict__ b1p) {
  int g = blockIdx.x * blockDim.x + threadIdx.x;
  int e = g >> 13, r = g & (TWO_H - 1);
  int h = r >> 1, p = r & 1;
  b1p[g] = b1[e * TWO_H + p * HID + h];
}

// ---------------- router: logits, softmax stats, top-2, gates ----------------
__global__ void __launch_bounds__(256) k_router(
    const float* __restrict__ x, const float* __restrict__ Wr, const float* __restrict__ br,
    int* __restrict__ idx, float* __restrict__ gate,
    float* __restrict__ imp, float* __restrict__ zsum) {
  int n = blockIdx.x, tid = threadIdx.x;
  int e = tid & 7, part = tid >> 3;                 // 32 partials per expert
  const float* xr = x + (size_t)n * DIM;
  float s = 0.f;
  for (int j = 0; j < DIM / 32; ++j) {
    int k = part + j * 32;
    s += xr[k] * Wr[k * NEXP + e];
  }
  __shared__ float red[256];
  __shared__ float lg[NEXP];
  red[tid] = s;
  __syncthreads();
  if (tid < NEXP) {
    float t = br[tid];
    for (int j = 0; j < 32; ++j) t += red[tid + j * 8];
    lg[tid] = t;
  }
  __syncthreads();
  if (tid == 0) {
    float mx = lg[0];
    for (int i = 1; i < 8; ++i) mx = fmaxf(mx, lg[i]);
    float ex[8], den = 0.f, zs = 0.f;
    for (int i = 0; i < 8; ++i) { ex[i] = expf(lg[i] - mx); den += ex[i]; zs += lg[i] * lg[i]; }
    atomicAdd(zsum, zs);
    for (int i = 0; i < 8; ++i) atomicAdd(&imp[i], ex[i] / den);
    int i1 = 0;
    for (int i = 1; i < 8; ++i) if (lg[i] > lg[i1]) i1 = i;     // ties -> lowest idx, like top_k
    int i2 = -1;
    for (int i = 0; i < 8; ++i) { if (i == i1) continue; if (i2 < 0 || lg[i] > lg[i2]) i2 = i; }
    float e2 = expf(lg[i2] - lg[i1]);
    float g1 = 1.f / (1.f + e2);
    idx[n * 2] = i1; idx[n * 2 + 1] = i2;
    gate[n * 2] = g1; gate[n * 2 + 1] = 1.f - g1;
  }
}

// ---------------- per-expert sequential position scan (flat order s = k*N + n) -----
__global__ void k_scan(const int* __restrict__ idx, int* __restrict__ pos, int* __restrict__ cnt) {
  int wave = threadIdx.x >> 6, lane = threadIdx.x & 63;  // wave == expert id
  int base = 0;
  for (int c = 0; c < (2 * N_TOK) / 64; ++c) {
    int s = c * 64 + lane;
    int n = s & (N_TOK - 1), k = s >> 12;
    int e = idx[n * 2 + k];
    unsigned long long m = __ballot(e == wave);
    if (e == wave) pos[s] = base + __popcll(m & ((1ull << lane) - 1ull));
    base += __popcll(m);
  }
  if (lane == 0) cnt[wave] = base;
}

// ---------------- renormalized kept gates ----------------
__global__ void k_weights(const float* __restrict__ gate, const int* __restrict__ pos,
                          float* __restrict__ wn) {
  int n = blockIdx.x * blockDim.x + threadIdx.x;
  if (n >= N_TOK) return;
  float g0 = gate[n * 2], g1 = gate[n * 2 + 1];
  float k0 = (pos[n] < CAP) ? g0 : 0.f;
  float k1 = (pos[N_TOK + n] < CAP) ? g1 : 0.f;
  float den = fmaxf(k0 + k1, 1e-8f);
  wn[n * 2] = k0 / den; wn[n * 2 + 1] = k1 / den;
}

// ---------------- gather + per-expert LayerNorm -> Xn bf16 [E][CAP][D] ----------------
__global__ void __launch_bounds__(256) k_gather_ln(
    const float* __restrict__ x, const float* __restrict__ lns, const float* __restrict__ lnb,
    const int* __restrict__ idx, const int* __restrict__ pos, unsigned short* __restrict__ Xn) {
  int s = blockIdx.x;
  int p = pos[s];
  if (p >= CAP) return;                       // dropped slot; Xn row stays poison (tiny bf16, *0 later)
  int n = s & (N_TOK - 1), k = s >> 12;
  int e = idx[n * 2 + k];
  const float* xr = x + (size_t)n * DIM;
  int tid = threadIdx.x;
  float v[4], sum = 0.f, sq = 0.f;
  for (int i = 0; i < 4; ++i) { v[i] = xr[tid + i * 256]; sum += v[i]; sq += v[i] * v[i]; }
  for (int o = 32; o > 0; o >>= 1) { sum += __shfl_down(sum, o); sq += __shfl_down(sq, o); }
  __shared__ float ws[8];
  int wv = tid >> 6, ln = tid & 63;
  if (ln == 0) { ws[wv] = sum; ws[4 + wv] = sq; }
  __syncthreads();
  sum = ws[0] + ws[1] + ws[2] + ws[3];
  sq  = ws[4] + ws[5] + ws[6] + ws[7];
  float mu = sum * (1.f / DIM);
  float var = sq * (1.f / DIM) - mu * mu;
  float rs = rsqrtf(var + 1e-5f);
  unsigned short* orow = Xn + ((size_t)e * CAP + p) * DIM;
  const float* sc = lns + (size_t)e * DIM;
  const float* bi = lnb + (size_t)e * DIM;
  for (int i = 0; i < 4; ++i) {
    int d = tid + i * 256;
    orow[d] = f2bf((v[i] - mu) * rs * sc[d] + bi[d]);
  }
}

// ---------------- bf16 MFMA GEMM: C[m][n] = sum_k A[m][k] * B[n][k]  (B is N-major, B^T) ----
// 128x128 tile, BK=64, 4 waves (2x2 of 64x64), 16x16x32 MFMA.
// GLU=true: B rows are packed (a,g) pairs; epilogue writes V[m][n/2] = (a+b1a)*sigmoid(g+b1g) bf16
// Epilogue is staged through LDS (reusing the K-loop buffers) so all global
// stores are full-wave dwordx4 (128B-line granular). Direct sub-dword scattered
// stores cost 5.1 GB of HBM writes (measured R1, 61x amplification).
template<bool GLU>
__global__ void __launch_bounds__(256) k_gemm(
    const unsigned short* __restrict__ A,   // [E][M][K]
    const unsigned short* __restrict__ B,   // [E][Nn][K]
    const float* __restrict__ bias,         // b1p [E][2H] (only used if GLU)
    unsigned short* __restrict__ Cout,      // GLU: [E][M][Nn/2] else [E][M][Nn]
    int M, int Nn, int K) {
  __shared__ __align__(16) unsigned short smem[2 * 128 * 72];   // 36 KB
  unsigned short* sA = smem;            // [128][72]
  unsigned short* sB = smem + 128 * 72; // [128][72]
  int e  = blockIdx.z;
  int m0 = blockIdx.y * 128;
  int n0 = blockIdx.x * 128;
  const unsigned short* Ae = A + (size_t)e * M * K;
  const unsigned short* Be = B + (size_t)e * Nn * K;
  int tid = threadIdx.x;
  int lane = tid & 63, wave = tid >> 6;
  int wm = (wave >> 1) * 64, wn = (wave & 1) * 64;
  int quad = lane >> 4, l16 = lane & 15;
  f32x4 acc[4][4];
  for (int i = 0; i < 4; ++i)
    for (int j = 0; j < 4; ++j) acc[i][j] = f32x4{0.f, 0.f, 0.f, 0.f};

  int srow = tid >> 3;              // 0..31
  int schunk = (tid & 7) * 8;       // element offset within 64-wide K slab
  for (int k0 = 0; k0 < K; k0 += 64) {
    __syncthreads();
    for (int i = 0; i < 4; ++i) {
      int r = srow + i * 32;
      *(int4*)&sA[r * 72 + schunk] = *(const int4*)&Ae[(size_t)(m0 + r) * K + k0 + schunk];
      *(int4*)&sB[r * 72 + schunk] = *(const int4*)&Be[(size_t)(n0 + r) * K + k0 + schunk];
    }
    __syncthreads();
    for (int kk = 0; kk < 64; kk += 32) {
      bf16x8 aF[4], bF[4];
      for (int i = 0; i < 4; ++i) {
        aF[i] = *(const bf16x8*)&sA[(wm + i * 16 + l16) * 72 + kk + quad * 8];
        bF[i] = *(const bf16x8*)&sB[(wn + i * 16 + l16) * 72 + kk + quad * 8];
      }
      for (int i = 0; i < 4; ++i)
        for (int j = 0; j < 4; ++j)
          acc[i][j] = __builtin_amdgcn_mfma_f32_16x16x32_bf16(aF[i], bF[j], acc[i][j], 0, 0, 0);
    }
  }
  __syncthreads();   // K-loop LDS reads done in all waves; smem is reused below
  if (GLU) {
    const float* bp = bias + (size_t)e * TWO_H;
    unsigned short* Ce = Cout + (size_t)e * M * (Nn >> 1);
    // stage packed GLU output tile: [128 rows][64 shorts], row stride 80 (160B, 16B-mult)
    for (int i = 0; i < 4; ++i)
      for (int j = 0; j < 4; ++j) {
        int pn = n0 + wn + j * 16 + l16;
        float b = bp[pn];
        for (int r = 0; r < 4; ++r) {
          int row = wm + i * 16 + quad * 4 + r;
          float u = acc[i][j][r] + b;          // includes bias for both a and g lanes
          float g = __shfl_xor(u, 1);          // partner column (pn^1)
          if ((l16 & 1) == 0) {                // even col = a, partner = g
            float vv = u / (1.f + __expf(-g));
            smem[row * 80 + ((wn + j * 16 + l16) >> 1)] = f2bf(vv);
          }
        }
      }
    __syncthreads();
    // cooperative coalesced store: 64 shorts (128B) per row, 8 lanes x int4
    int c = tid & 7, row0 = tid >> 3;
    for (int p = 0; p < 4; ++p) {
      int row = row0 + p * 32;
      *(int4*)&Ce[(size_t)(m0 + row) * (Nn >> 1) + (n0 >> 1) + c * 8] =
          *(const int4*)&smem[row * 80 + c * 8];
    }
  } else {
    unsigned short* Ce = Cout + (size_t)e * M * Nn;
    // stage output tile: [128 rows][128 shorts], row stride 136 (272B, 16B-mult)
    for (int i = 0; i < 4; ++i)
      for (int j = 0; j < 4; ++j) {
        int col = wn + j * 16 + l16;
        for (int r = 0; r < 4; ++r) {
          int row = wm + i * 16 + quad * 4 + r;
          smem[row * 136 + col] = f2bf(acc[i][j][r]);
        }
      }
    __syncthreads();
    // cooperative coalesced store: 128 shorts (256B) per row, 16 lanes x int4
    int c = tid & 15, row0 = tid >> 4;
    for (int p = 0; p < 8; ++p) {
      int row = row0 + p * 16;
      *(int4*)&Ce[(size_t)(m0 + row) * Nn + n0 + c * 8] =
          *(const int4*)&smem[row * 136 + c * 8];
    }
  }
}

// ---------------- combine: y[n] = sum_k w_k * (Yexp[e_k][p_k] + b2[e_k]) ----------------
__global__ void __launch_bounds__(256) k_gather_out(
    const unsigned short* __restrict__ Yexp, const float* __restrict__ b2,
    const int* __restrict__ idx, const int* __restrict__ pos,
    const float* __restrict__ wn, float* __restrict__ y) {
  int n = blockIdx.x, tid = threadIdx.x;
  int e0 = idx[n * 2], e1 = idx[n * 2 + 1];
  int p0 = min(pos[n], CAP - 1), p1 = min(pos[N_TOK + n], CAP - 1);
  float w0 = wn[n * 2], w1 = wn[n * 2 + 1];
  const unsigned short* r0 = Yexp + ((size_t)e0 * CAP + p0) * DIM;
  const unsigned short* r1 = Yexp + ((size_t)e1 * CAP + p1) * DIM;
  const float* bb0 = b2 + (size_t)e0 * DIM;
  const float* bb1 = b2 + (size_t)e1 * DIM;
  float* yr = y + (size_t)n * DIM;
  for (int i = 0; i < 4; ++i) {
    int d = tid + i * 256;
    yr[d] = w0 * (bf2f(r0[d]) + bb0[d]) + w1 * (bf2f(r1[d]) + bb1[d]);
  }
}

// ---------------- scalar losses ----------------
__global__ void k_losses(const float* __restrict__ imp, const int* __restrict__ cnt,
                         const float* __restrict__ zsum, float* __restrict__ out) {
  if (threadIdx.x != 0 || blockIdx.x != 0) return;
  double li[8], ll[8], mi = 0.0, ml = 0.0;
  for (int i = 0; i < 8; ++i) {
    li[i] = imp[i];
    ll[i] = (double)min(cnt[i], CAP);
    mi += li[i]; ml += ll[i];
  }
  mi /= 8.0; ml /= 8.0;
  double vi = 0.0, vl = 0.0;
  for (int i = 0; i < 8; ++i) { vi += (li[i] - mi) * (li[i] - mi); vl += (ll[i] - ml) * (ll[i] - ml); }
  vi /= 8.0; vl /= 8.0;
  const double eps = 1e-9;
  double cvi = vi / (fmax(mi, eps) * fmax(mi, eps) + eps);
  double cvl = vl / (fmax(ml, eps) * fmax(ml, eps) + eps);
  out[0] = (float)(0.5 * (cvi + cvl));
  out[1] = (float)((double)zsum[0] / (double)(N_TOK * NEXP) * 1e-4);
}

extern "C" void kernel_launch(void* const* d_in, const int* in_sizes, int n_in,
                              void* d_out, int out_size, void* d_ws, size_t ws_size,
                              hipStream_t stream) {
  const float* h   = (const float*)d_in[0];
  const float* Wr  = (const float*)d_in[1];
  const float* br  = (const float*)d_in[2];
  const float* lns = (const float*)d_in[3];
  const float* lnb = (const float*)d_in[4];
  const float* W1  = (const float*)d_in[5];
  const float* b1  = (const float*)d_in[6];
  const float* W2  = (const float*)d_in[7];
  const float* b2  = (const float*)d_in[8];
  float* out = (float*)d_out;

  char* ws = (char*)d_ws;
  size_t off = 0;
  auto alloc = [&](size_t bytes) { char* p = ws + off; off += (bytes + 255) & ~(size_t)255; return p; };
  unsigned short* W1t = (unsigned short*)alloc((size_t)NEXP * TWO_H * DIM * 2);  // 134 MB
  unsigned short* W2t = (unsigned short*)alloc((size_t)NEXP * DIM * HID * 2);    // 67 MB
  unsigned short* Xn  = (unsigned short*)alloc((size_t)NEXP * CAP * DIM * 2);    // 21 MB
  unsigned short* V   = (unsigned short*)alloc((size_t)NEXP * CAP * HID * 2);    // 84 MB
  unsigned short* Yx  = (unsigned short*)alloc((size_t)NEXP * CAP * DIM * 2);    // 21 MB
  float* b1p  = (float*)alloc((size_t)NEXP * TWO_H * 4);
  int*   idx  = (int*)alloc((size_t)N_TOK * 2 * 4);
  float* gate = (float*)alloc((size_t)N_TOK * 2 * 4);
  float* wn   = (float*)alloc((size_t)N_TOK * 2 * 4);
  int*   pos  = (int*)alloc((size_t)2 * N_TOK * 4);
  int*   cnt  = (int*)alloc(64);
  float* imp  = (float*)alloc(64);
  float* zsum = (float*)alloc(64);
  (void)ws_size; (void)in_sizes; (void)n_in; (void)out_size;

  k_zero<<<dim3(1), dim3(64), 0, stream>>>(imp, zsum);
  k_conv_w1<<<dim3(HID / 32, DIM / 32, NEXP), dim3(256), 0, stream>>>(W1, W1t);
  k_conv_w2<<<dim3(DIM / 32, HID / 32, NEXP), dim3(256), 0, stream>>>(W2, W2t);
  k_pack_b1<<<dim3(NEXP * TWO_H / 256), dim3(256), 0, stream>>>(b1, b1p);
  k_router<<<dim3(N_TOK), dim3(256), 0, stream>>>(h, Wr, br, idx, gate, imp, zsum);
  k_scan<<<dim3(1), dim3(512), 0, stream>>>(idx, pos, cnt);
  k_weights<<<dim3(16), dim3(256), 0, stream>>>(gate, pos, wn);
  k_gather_ln<<<dim3(2 * N_TOK), dim3(256), 0, stream>>>(h, lns, lnb, idx, pos, Xn);
  k_gemm<true><<<dim3(TWO_H / 128, CAP / 128, NEXP), dim3(256), 0, stream>>>(
      Xn, W1t, b1p, V, CAP, TWO_H, DIM);
  k_gemm<false><<<dim3(DIM / 128, CAP / 128, NEXP), dim3(256), 0, stream>>>(
      V, W2t, b1p, Yx, CAP, DIM, HID);
  k_gather_out<<<dim3(N_TOK), dim3(256), 0, stream>>>(Yx, b2, idx, pos, wn, out);
  k_losses<<<dim3(1), dim3(64), 0, stream>>>(imp, cnt, zsum, out + (size_t)N_TOK * DIM);
}

// Round 3
// 1071.802 us; speedup vs baseline: 2.1319x; 1.3565x over previous
//
#include <hip/hip_runtime.h>
#include <cstdint>
#include <cstddef>

#define N_TOK 4096
#define DIM   1024
#define NEXP  8
#define HID   4096
#define TWO_H 8192
#define CAP   1280

typedef __bf16 bf16x8 __attribute__((ext_vector_type(8)));
typedef float  f32x4  __attribute__((ext_vector_type(4)));

__device__ __forceinline__ unsigned short f2bf(float f) {
  union { float f; unsigned u; } v; v.f = f;
  unsigned r = v.u + 0x7FFF + ((v.u >> 16) & 1);   // RNE
  return (unsigned short)(r >> 16);
}
__device__ __forceinline__ float bf2f(unsigned short b) {
  union { unsigned u; float f; } v; v.u = ((unsigned)b) << 16;
  return v.f;
}

// ---------------- zero accumulators ----------------
__global__ void k_zero(float* imp, float* zsum) {
  if (threadIdx.x < NEXP) imp[threadIdx.x] = 0.f;
  if (threadIdx.x == 0) zsum[0] = 0.f;
}

// ---------------- W1 [E][D][2H] fp32 -> packed W1t [E][2H][D] bf16 ----------------
__global__ void k_conv_w1(const float* __restrict__ W1, unsigned short* __restrict__ W1t) {
  __shared__ float tA[32][33];
  __shared__ float tG[32][33];
  int h0 = blockIdx.x * 32, d0 = blockIdx.y * 32, e = blockIdx.z;
  int tx = threadIdx.x & 31, ty = threadIdx.x >> 5;  // ty 0..7
  const float* src = W1 + (size_t)e * DIM * TWO_H;
  for (int i = 0; i < 32; i += 8) {
    int d = d0 + ty + i;
    tA[ty + i][tx] = src[(size_t)d * TWO_H + h0 + tx];
    tG[ty + i][tx] = src[(size_t)d * TWO_H + HID + h0 + tx];
  }
  __syncthreads();
  unsigned short* dst = W1t + (size_t)e * TWO_H * DIM;
  for (int i = 0; i < 64; i += 8) {
    int r = ty + i;                  // 0..63 local packed row
    int hh = r >> 1, p = r & 1;
    float v = p ? tG[tx][hh] : tA[tx][hh];
    dst[(size_t)(2 * h0 + r) * DIM + d0 + tx] = f2bf(v);
  }
}

// ---------------- W2 [E][H][D] fp32 -> W2t [E][D][H] bf16 ----------------
__global__ void k_conv_w2(const float* __restrict__ W2, unsigned short* __restrict__ W2t) {
  __shared__ float t[32][33];
  int d0 = blockIdx.x * 32, h0 = blockIdx.y * 32, e = blockIdx.z;
  int tx = threadIdx.x & 31, ty = threadIdx.x >> 5;
  const float* src = W2 + (size_t)e * HID * DIM;
  for (int i = 0; i < 32; i += 8)
    t[ty + i][tx] = src[(size_t)(h0 + ty + i) * DIM + d0 + tx];
  __syncthreads();
  unsigned short* dst = W2t + (size_t)e * DIM * HID;
  for (int i = 0; i < 32; i += 8)
    dst[(size_t)(d0 + ty + i) * HID + h0 + tx] = f2bf(t[tx][ty + i]);
}

// ---------------- b1 [E][2H] -> packed b1p [E][2H] (pairs a,g) ----------------
__global__ void k_pack_b1(const float* __restrict__ b1, float* __restrict__ b1p) {
  int g = blockIdx.x * blockDim.x + threadIdx.x;
  int e = g >> 13, r = g & (TWO_H - 1);
  int h = r >> 1, p = r & 1;
  b1p[g] = b1[e * TWO_H + p * HID + h];
}

// ---------------- router v2: 16 tokens/block, block-local reduction ----------------
// R2 post-mortem: v1 had 4096 blocks x 9 same-address global atomics = 421 us of
// atomic serialization. v2: 256 blocks, LDS-accumulated imp/zsum, 9 atomics/block.
__global__ void __launch_bounds__(256) k_router(
    const float* __restrict__ x, const float* __restrict__ Wr, const float* __restrict__ br,
    int* __restrict__ idx, float* __restrict__ gate,
    float* __restrict__ imp, float* __restrict__ zsum) {
  // sX row stride 1028 floats (4112B): token rows land on different bank groups
  __shared__ float sW[TWO_H];          // 32 KB  (Wr is [D][E] = 1024*8)
  __shared__ float sX[16 * 1028];      // 65.8 KB
  __shared__ float sLG[16 * 8];
  __shared__ float sImp[8];
  __shared__ float sZ;
  int tid = threadIdx.x;
  if (tid < 8) sImp[tid] = 0.f;
  if (tid == 8) sZ = 0.f;
  for (int i = 0; i < 8; ++i) {
    int g = tid + i * 256;
    *(float4*)&sW[g * 4] = *(const float4*)&Wr[g * 4];
  }
  int t0 = blockIdx.x * 16;
  const float* xb = x + (size_t)t0 * DIM;
  for (int i = 0; i < 16; ++i) {
    int g = tid + i * 256;           // global float4 index within 16 rows
    int row = g >> 8, c = (g & 255) * 4;
    *(float4*)&sX[row * 1028 + c] = *(const float4*)&xb[(size_t)g * 4];
  }
  __syncthreads();
  int t = tid >> 4, e = (tid >> 1) & 7, half = tid & 1;
  const float* xr = &sX[t * 1028 + half * 512];
  float s = 0.f;
  for (int k = 0; k < 512; k += 4) {
    float4 xv = *(const float4*)&xr[k];
    int kb = (half * 512 + k) * 8 + e;
    s += xv.x * sW[kb] + xv.y * sW[kb + 8] + xv.z * sW[kb + 16] + xv.w * sW[kb + 24];
  }
  s += __shfl_xor(s, 1);               // combine the two K-halves
  if (half == 0) sLG[t * 8 + e] = s + br[e];
  __syncthreads();
  if (tid < 16) {
    int n = t0 + tid;
    float lg[8];
    for (int i = 0; i < 8; ++i) lg[i] = sLG[tid * 8 + i];
    float mx = lg[0];
    for (int i = 1; i < 8; ++i) mx = fmaxf(mx, lg[i]);
    float ex[8], den = 0.f, zs = 0.f;
    for (int i = 0; i < 8; ++i) { ex[i] = __expf(lg[i] - mx); den += ex[i]; zs += lg[i] * lg[i]; }
    atomicAdd(&sZ, zs);
    float rden = 1.f / den;
    for (int i = 0; i < 8; ++i) atomicAdd(&sImp[i], ex[i] * rden);
    int i1 = 0;
    for (int i = 1; i < 8; ++i) if (lg[i] > lg[i1]) i1 = i;     // ties -> lowest idx, like top_k
    int i2 = -1;
    for (int i = 0; i < 8; ++i) { if (i == i1) continue; if (i2 < 0 || lg[i] > lg[i2]) i2 = i; }
    float e2 = __expf(lg[i2] - lg[i1]);
    float g1 = 1.f / (1.f + e2);
    idx[n * 2] = i1; idx[n * 2 + 1] = i2;
    gate[n * 2] = g1; gate[n * 2 + 1] = 1.f - g1;
  }
  __syncthreads();
  if (tid < 8) atomicAdd(&imp[tid], sImp[tid]);
  if (tid == 8) atomicAdd(zsum, sZ);
}

// ---------------- per-expert sequential position scan (flat order s = k*N + n) -----
__global__ void k_scan(const int* __restrict__ idx, int* __restrict__ pos, int* __restrict__ cnt) {
  int wave = threadIdx.x >> 6, lane = threadIdx.x & 63;  // wave == expert id
  int base = 0;
  for (int c = 0; c < (2 * N_TOK) / 64; ++c) {
    int s = c * 64 + lane;
    int n = s & (N_TOK - 1), k = s >> 12;
    int e = idx[n * 2 + k];
    unsigned long long m = __ballot(e == wave);
    if (e == wave) pos[s] = base + __popcll(m & ((1ull << lane) - 1ull));
    base += __popcll(m);
  }
  if (lane == 0) cnt[wave] = base;
}

// ---------------- renormalized kept gates ----------------
__global__ void k_weights(const float* __restrict__ gate, const int* __restrict__ pos,
                          float* __restrict__ wn) {
  int n = blockIdx.x * blockDim.x + threadIdx.x;
  if (n >= N_TOK) return;
  float g0 = gate[n * 2], g1 = gate[n * 2 + 1];
  float k0 = (pos[n] < CAP) ? g0 : 0.f;
  float k1 = (pos[N_TOK + n] < CAP) ? g1 : 0.f;
  float den = fmaxf(k0 + k1, 1e-8f);
  wn[n * 2] = k0 / den; wn[n * 2 + 1] = k1 / den;
}

// ---------------- gather + per-expert LayerNorm -> Xn bf16 [E][CAP][D] ----------------
__global__ void __launch_bounds__(256) k_gather_ln(
    const float* __restrict__ x, const float* __restrict__ lns, const float* __restrict__ lnb,
    const int* __restrict__ idx, const int* __restrict__ pos, unsigned short* __restrict__ Xn) {
  int s = blockIdx.x;
  int p = pos[s];
  if (p >= CAP) return;                       // dropped slot; Xn row stays poison (tiny bf16, *0 later)
  int n = s & (N_TOK - 1), k = s >> 12;
  int e = idx[n * 2 + k];
  const float* xr = x + (size_t)n * DIM;
  int tid = threadIdx.x;
  float v[4], sum = 0.f, sq = 0.f;
  for (int i = 0; i < 4; ++i) { v[i] = xr[tid + i * 256]; sum += v[i]; sq += v[i] * v[i]; }
  for (int o = 32; o > 0; o >>= 1) { sum += __shfl_down(sum, o); sq += __shfl_down(sq, o); }
  __shared__ float ws[8];
  int wv = tid >> 6, ln = tid & 63;
  if (ln == 0) { ws[wv] = sum; ws[4 + wv] = sq; }
  __syncthreads();
  sum = ws[0] + ws[1] + ws[2] + ws[3];
  sq  = ws[4] + ws[5] + ws[6] + ws[7];
  float mu = sum * (1.f / DIM);
  float var = sq * (1.f / DIM) - mu * mu;
  float rs = rsqrtf(var + 1e-5f);
  unsigned short* orow = Xn + ((size_t)e * CAP + p) * DIM;
  const float* sc = lns + (size_t)e * DIM;
  const float* bi = lnb + (size_t)e * DIM;
  for (int i = 0; i < 4; ++i) {
    int d = tid + i * 256;
    orow[d] = f2bf((v[i] - mu) * rs * sc[d] + bi[d]);
  }
}

// ---------------- bf16 MFMA GEMM: C[m][n] = sum_k A[m][k] * B[n][k]  (B is N-major, B^T) ----
// 128x128 tile, BK=64, 4 waves (2x2 of 64x64), 16x16x32 MFMA.
// Grid: blockIdx.x = m-tile (FASTEST) so the m-blocks sharing one B n-tile are
// temporally adjacent -> B tile fetched from HBM once, re-served from L2/L3.
// GLU=true: B rows are packed (a,g) pairs; epilogue writes V[m][n/2] = a*sigmoid(g) bf16
// Epilogue staged through LDS so all global stores are full-line dwordx4
// (direct sub-dword scattered stores cost 5.1 GB HBM writes - measured R1).
template<bool GLU>
__global__ void __launch_bounds__(256) k_gemm(
    const unsigned short* __restrict__ A,   // [E][M][K]
    const unsigned short* __restrict__ B,   // [E][Nn][K]
    const float* __restrict__ bias,         // b1p [E][2H] (only used if GLU)
    unsigned short* __restrict__ Cout,      // GLU: [E][M][Nn/2] else [E][M][Nn]
    int M, int Nn, int K) {
  __shared__ __align__(16) unsigned short smem[2 * 128 * 72];   // 36 KB
  unsigned short* sA = smem;            // [128][72]
  unsigned short* sB = smem + 128 * 72; // [128][72]
  int e  = blockIdx.z;
  int m0 = blockIdx.x * 128;
  int n0 = blockIdx.y * 128;
  const unsigned short* Ae = A + (size_t)e * M * K;
  const unsigned short* Be = B + (size_t)e * Nn * K;
  int tid = threadIdx.x;
  int lane = tid & 63, wave = tid >> 6;
  int wm = (wave >> 1) * 64, wn = (wave & 1) * 64;
  int quad = lane >> 4, l16 = lane & 15;
  f32x4 acc[4][4];
  for (int i = 0; i < 4; ++i)
    for (int j = 0; j < 4; ++j) acc[i][j] = f32x4{0.f, 0.f, 0.f, 0.f};

  int srow = tid >> 3;              // 0..31
  int schunk = (tid & 7) * 8;       // element offset within 64-wide K slab
  for (int k0 = 0; k0 < K; k0 += 64) {
    __syncthreads();
    for (int i = 0; i < 4; ++i) {
      int r = srow + i * 32;
      *(int4*)&sA[r * 72 + schunk] = *(const int4*)&Ae[(size_t)(m0 + r) * K + k0 + schunk];
      *(int4*)&sB[r * 72 + schunk] = *(const int4*)&Be[(size_t)(n0 + r) * K + k0 + schunk];
    }
    __syncthreads();
    for (int kk = 0; kk < 64; kk += 32) {
      bf16x8 aF[4], bF[4];
      for (int i = 0; i < 4; ++i) {
        aF[i] = *(const bf16x8*)&sA[(wm + i * 16 + l16) * 72 + kk + quad * 8];
        bF[i] = *(const bf16x8*)&sB[(wn + i * 16 + l16) * 72 + kk + quad * 8];
      }
      for (int i = 0; i < 4; ++i)
        for (int j = 0; j < 4; ++j)
          acc[i][j] = __builtin_amdgcn_mfma_f32_16x16x32_bf16(aF[i], bF[j], acc[i][j], 0, 0, 0);
    }
  }
  __syncthreads();   // K-loop LDS reads done in all waves; smem is reused below
  if (GLU) {
    const float* bp = bias + (size_t)e * TWO_H;
    unsigned short* Ce = Cout + (size_t)e * M * (Nn >> 1);
    // stage packed GLU output tile: [128 rows][64 shorts], row stride 80 (160B, 16B-mult)
    for (int i = 0; i < 4; ++i)
      for (int j = 0; j < 4; ++j) {
        int pn = n0 + wn + j * 16 + l16;
        float b = bp[pn];
        for (int r = 0; r < 4; ++r) {
          int row = wm + i * 16 + quad * 4 + r;
          float u = acc[i][j][r] + b;          // includes bias for both a and g lanes
          float g = __shfl_xor(u, 1);          // partner column (pn^1)
          if ((l16 & 1) == 0) {                // even col = a, partner = g
            float vv = u / (1.f + __expf(-g));
            smem[row * 80 + ((wn + j * 16 + l16) >> 1)] = f2bf(vv);
          }
        }
      }
    __syncthreads();
    // cooperative coalesced store: 64 shorts (128B) per row, 8 lanes x int4
    int c = tid & 7, row0 = tid >> 3;
    for (int p = 0; p < 4; ++p) {
      int row = row0 + p * 32;
      *(int4*)&Ce[(size_t)(m0 + row) * (Nn >> 1) + (n0 >> 1) + c * 8] =
          *(const int4*)&smem[row * 80 + c * 8];
    }
  } else {
    unsigned short* Ce = Cout + (size_t)e * M * Nn;
    // stage output tile: [128 rows][128 shorts], row stride 136 (272B, 16B-mult)
    for (int i = 0; i < 4; ++i)
      for (int j = 0; j < 4; ++j) {
        int col = wn + j * 16 + l16;
        for (int r = 0; r < 4; ++r) {
          int row = wm + i * 16 + quad * 4 + r;
          smem[row * 136 + col] = f2bf(acc[i][j][r]);
        }
      }
    __syncthreads();
    // cooperative coalesced store: 128 shorts (256B) per row, 16 lanes x int4
    int c = tid & 15, row0 = tid >> 4;
    for (int p = 0; p < 8; ++p) {
      int row = row0 + p * 16;
      *(int4*)&Ce[(size_t)(m0 + row) * Nn + n0 + c * 8] =
          *(const int4*)&smem[row * 136 + c * 8];
    }
  }
}

// ---------------- combine: y[n] = sum_k w_k * (Yexp[e_k][p_k] + b2[e_k]) ----------------
__global__ void __launch_bounds__(256) k_gather_out(
    const unsigned short* __restrict__ Yexp, const float* __restrict__ b2,
    const int* __restrict__ idx, const int* __restrict__ pos,
    const float* __restrict__ wn, float* __restrict__ y) {
  int n = blockIdx.x, tid = threadIdx.x;
  int e0 = idx[n * 2], e1 = idx[n * 2 + 1];
  int p0 = min(pos[n], CAP - 1), p1 = min(pos[N_TOK + n], CAP - 1);
  float w0 = wn[n * 2], w1 = wn[n * 2 + 1];
  const unsigned short* r0 = Yexp + ((size_t)e0 * CAP + p0) * DIM;
  const unsigned short* r1 = Yexp + ((size_t)e1 * CAP + p1) * DIM;
  const float* bb0 = b2 + (size_t)e0 * DIM;
  const float* bb1 = b2 + (size_t)e1 * DIM;
  float* yr = y + (size_t)n * DIM;
  for (int i = 0; i < 4; ++i) {
    int d = tid + i * 256;
    yr[d] = w0 * (bf2f(r0[d]) + bb0[d]) + w1 * (bf2f(r1[d]) + bb1[d]);
  }
}

// ---------------- scalar losses ----------------
__global__ void k_losses(const float* __restrict__ imp, const int* __restrict__ cnt,
                         const float* __restrict__ zsum, float* __restrict__ out) {
  if (threadIdx.x != 0 || blockIdx.x != 0) return;
  double li[8], ll[8], mi = 0.0, ml = 0.0;
  for (int i = 0; i < 8; ++i) {
    li[i] = imp[i];
    ll[i] = (double)min(cnt[i], CAP);
    mi += li[i]; ml += ll[i];
  }
  mi /= 8.0; ml /= 8.0;
  double vi = 0.0, vl = 0.0;
  for (int i = 0; i < 8; ++i) { vi += (li[i] - mi) * (li[i] - mi); vl += (ll[i] - ml) * (ll[i] - ml); }
  vi /= 8.0; vl /= 8.0;
  const double eps = 1e-9;
  double cvi = vi / (fmax(mi, eps) * fmax(mi, eps) + eps);
  double cvl = vl / (fmax(ml, eps) * fmax(ml, eps) + eps);
  out[0] = (float)(0.5 * (cvi + cvl));
  out[1] = (float)((double)zsum[0] / (double)(N_TOK * NEXP) * 1e-4);
}

extern "C" void kernel_launch(void* const* d_in, const int* in_sizes, int n_in,
                              void* d_out, int out_size, void* d_ws, size_t ws_size,
                              hipStream_t stream) {
  const float* h   = (const float*)d_in[0];
  const float* Wr  = (const float*)d_in[1];
  const float* br  = (const float*)d_in[2];
  const float* lns = (const float*)d_in[3];
  const float* lnb = (const float*)d_in[4];
  const float* W1  = (const float*)d_in[5];
  const float* b1  = (const float*)d_in[6];
  const float* W2  = (const float*)d_in[7];
  const float* b2  = (const float*)d_in[8];
  float* out = (float*)d_out;

  char* ws = (char*)d_ws;
  size_t off = 0;
  auto alloc = [&](size_t bytes) { char* p = ws + off; off += (bytes + 255) & ~(size_t)255; return p; };
  unsigned short* W1t = (unsigned short*)alloc((size_t)NEXP * TWO_H * DIM * 2);  // 134 MB
  unsigned short* W2t = (unsigned short*)alloc((size_t)NEXP * DIM * HID * 2);    // 67 MB
  unsigned short* Xn  = (unsigned short*)alloc((size_t)NEXP * CAP * DIM * 2);    // 21 MB
  unsigned short* V   = (unsigned short*)alloc((size_t)NEXP * CAP * HID * 2);    // 84 MB
  unsigned short* Yx  = (unsigned short*)alloc((size_t)NEXP * CAP * DIM * 2);    // 21 MB
  float* b1p  = (float*)alloc((size_t)NEXP * TWO_H * 4);
  int*   idx  = (int*)alloc((size_t)N_TOK * 2 * 4);
  float* gate = (float*)alloc((size_t)N_TOK * 2 * 4);
  float* wn   = (float*)alloc((size_t)N_TOK * 2 * 4);
  int*   pos  = (int*)alloc((size_t)2 * N_TOK * 4);
  int*   cnt  = (int*)alloc(64);
  float* imp  = (float*)alloc(64);
  float* zsum = (float*)alloc(64);
  (void)ws_size; (void)in_sizes; (void)n_in; (void)out_size;

  k_zero<<<dim3(1), dim3(64), 0, stream>>>(imp, zsum);
  k_conv_w1<<<dim3(HID / 32, DIM / 32, NEXP), dim3(256), 0, stream>>>(W1, W1t);
  k_conv_w2<<<dim3(DIM / 32, HID / 32, NEXP), dim3(256), 0, stream>>>(W2, W2t);
  k_pack_b1<<<dim3(NEXP * TWO_H / 256), dim3(256), 0, stream>>>(b1, b1p);
  k_router<<<dim3(N_TOK / 16), dim3(256), 0, stream>>>(h, Wr, br, idx, gate, imp, zsum);
  k_scan<<<dim3(1), dim3(512), 0, stream>>>(idx, pos, cnt);
  k_weights<<<dim3(16), dim3(256), 0, stream>>>(gate, pos, wn);
  k_gather_ln<<<dim3(2 * N_TOK), dim3(256), 0, stream>>>(h, lns, lnb, idx, pos, Xn);
  k_gemm<true><<<dim3(CAP / 128, TWO_H / 128, NEXP), dim3(256), 0, stream>>>(
      Xn, W1t, b1p, V, CAP, TWO_H, DIM);
  k_gemm<false><<<dim3(CAP / 128, DIM / 128, NEXP), dim3(256), 0, stream>>>(
      V, W2t, b1p, Yx, CAP, DIM, HID);
  k_gather_out<<<dim3(N_TOK), dim3(256), 0, stream>>>(Yx, b2, idx, pos, wn, out);
  k_losses<<<dim3(1), dim3(64), 0, stream>>>(imp, cnt, zsum, out + (size_t)N_TOK * DIM);
}